// Round 8
// baseline (288.388 us; speedup 1.0000x reference)
//
#include <hip/hip_runtime.h>
#include <hip/hip_bf16.h>
#include <stdint.h>

// GCN 2-layer forward: out = A_hat @ relu(A_hat @ (X W1^T + b1)) W2^T + b2
// A_hat = D^-1/2 (A + I) D^-1/2, pull-based CSR aggregation.
// GEMMs use bf16 MFMA (16x16x32), fp32 accumulate; epilogue pre-scales rows by
// dis[n], stores H' in BF16, and zeroes sentinel row N (tail gathers hit it).
// Agg v6: one wave per node, non-persistent (HW block backfill beats explicit
// persistent pipelines — measured R4). Row split across LPR lanes x 16B
// (uint4); quads of 16 edge-slots (KQ=16/G loads per quad), 2 quads deep.
// Tail edges gather sentinel row N (zeroed by gemm) -> no mask math;
// v_pk_add_f32 packed accumulate; nt stores/csr loads protect L2's H' lines.
// agg1 is at the L2-miss/L3 fabric ceiling for random 256B gathers:
// ~3.8 TB/s / FETCH ~187MB (~= 8 XCDs x footprint) across 5 structures.
// CSR build = R2's measured-best 4-launch counting sort, zero global atomics:
// hist (stages row32/col32 int32) -> colscan -> scatter (fused in-LDS
// binTotal scan, reads staged int32) -> finecsr (tree-reduce bucketStart).

#define TPB 256
#define NBLK_C 256            // edge chunks (blocks) in hist/scatter passes
#define TPB_C 1024            // threads per chunk block
#define MAX_NB 2048           // LDS arrays; scan paths assume NB <= 1024

typedef __attribute__((ext_vector_type(8))) __bf16 bf16x8;
typedef __attribute__((ext_vector_type(4))) float f32x4;
typedef __attribute__((ext_vector_type(2))) float f32x2;
typedef __attribute__((ext_vector_type(4))) unsigned int u32x4;

__device__ __forceinline__ float bf16lo(unsigned u) { return __uint_as_float(u << 16); }
__device__ __forceinline__ float bf16hi(unsigned u) { return __uint_as_float(u & 0xffff0000u); }
__device__ __forceinline__ unsigned short f2bf(float f) {
    unsigned u = __float_as_uint(f);
    return (unsigned short)((u + 0x7fff + ((u >> 16) & 1)) >> 16);  // RNE
}
// packed 2xfp32 add (VOP3P, full-rate): one instr for both bf16 halves
__device__ __forceinline__ f32x2 pk_add(f32x2 a, f32x2 b) {
    f32x2 d;
    asm("v_pk_add_f32 %0, %1, %2" : "=v"(d) : "v"(a), "v"(b));
    return d;
}

// ---------------------------------------------------------------------------
// K1: unpack edge_index -> row32/col32 staging AND per-block coarse-bucket
// histogram (bucket = row >> 7). Dtype probe (int64 vs int32) per-block by
// wave 0: int64 inputs (values < 2^31) have every odd 32-bit word of the
// first 64 row entries == 0. Validity predicate matches scatter exactly.
__global__ __launch_bounds__(TPB_C) void hist_extract_kernel(const void* __restrict__ ei, int E,
                                                             int CH,
                                                             int* __restrict__ row32,
                                                             int* __restrict__ col32,
                                                             int* __restrict__ hist,
                                                             int NB, int N) {
    __shared__ int h[MAX_NB];
    __shared__ int s_is64;
    int tid = threadIdx.x;
    if (tid < 64) {
        int x = ((const int*)ei)[2 * tid + 1];
        unsigned long long b = __ballot(x != 0);
        if (tid == 0) s_is64 = (b == 0ull);
    }
    for (int bin = tid; bin < NB; bin += TPB_C) h[bin] = 0;
    __syncthreads();

    int b = blockIdx.x;
    int s = b * CH;
    int end = min(E, s + CH);
    int is64 = s_is64;
    unsigned uN = (unsigned)N;
    if (is64) {
        const long long* p = (const long long*)ei;
        for (int e = s + tid; e < end; e += TPB_C) {
            int r = (int)p[e];
            int c = (int)p[E + e];
            row32[e] = r;
            col32[e] = c;
            if ((unsigned)r < uN && (unsigned)c < uN) atomicAdd(&h[r >> 7], 1);
        }
    } else {
        const int* p = (const int*)ei;
        for (int e = s + tid; e < end; e += TPB_C) {
            int r = p[e];
            int c = p[E + e];
            row32[e] = r;
            col32[e] = c;
            if ((unsigned)r < uN && (unsigned)c < uN) atomicAdd(&h[r >> 7], 1);
        }
    }
    __syncthreads();
    for (int bin = tid; bin < NB; bin += TPB_C) hist[bin * NBLK_C + b] = h[bin];
}

// ---------------------------------------------------------------------------
// K2: per-bucket exclusive scan across the NBLK_C block histograms (in place);
// emits binTotal[bin]. One block per bucket, TPB == NBLK_C.
__global__ __launch_bounds__(NBLK_C) void colscan_kernel(int* __restrict__ hist,
                                                         int* __restrict__ binTotal) {
    __shared__ int sm[NBLK_C];
    int bin = blockIdx.x;
    int tid = threadIdx.x;
    int v = hist[bin * NBLK_C + tid];
    sm[tid] = v;
    __syncthreads();
    for (int o = 1; o < NBLK_C; o <<= 1) {
        int x = (tid >= o) ? sm[tid - o] : 0;
        __syncthreads();
        sm[tid] += x;
        __syncthreads();
    }
    hist[bin * NBLK_C + tid] = sm[tid] - v;  // exclusive within bucket
    if (tid == NBLK_C - 1) binTotal[bin] = sm[NBLK_C - 1];
}

// ---------------------------------------------------------------------------
// K3: place edges into coarse buckets from staged int32. Per-block LDS
// cursors seeded from an in-kernel LDS scan of binTotal (bucketStart) +
// per-(bin,block) hist prefix; packed = (col<<7) | (row&127). NB <= 1024.
__global__ __launch_bounds__(TPB_C) void scatter_kernel(const int* __restrict__ row32,
                                                        const int* __restrict__ col32, int E,
                                                        int CH,
                                                        const int* __restrict__ hist,
                                                        const int* __restrict__ binTotal,
                                                        int* __restrict__ bucketed,
                                                        int NB, int N) {
    __shared__ int cur[MAX_NB];
    __shared__ int sm2[TPB_C];
    int tid = threadIdx.x;
    int b = blockIdx.x;

    // exclusive scan of binTotal (3KB, L2-hot) -> bucketStart, fused in-LDS
    int v = (tid < NB) ? binTotal[tid] : 0;
    sm2[tid] = v;
    __syncthreads();
    for (int o = 1; o < TPB_C; o <<= 1) {
        int x = (tid >= o) ? sm2[tid - o] : 0;
        __syncthreads();
        sm2[tid] += x;
        __syncthreads();
    }
    if (tid < NB) cur[tid] = (sm2[tid] - v) + hist[tid * NBLK_C + b];
    __syncthreads();

    int s = b * CH;
    int end = min(E, s + CH);
    unsigned uN = (unsigned)N;
    for (int e = s + tid; e < end; e += TPB_C) {
        int r = row32[e];
        int c = col32[e];
        if ((unsigned)r < uN && (unsigned)c < uN) {
            int pos = atomicAdd(&cur[r >> 7], 1);
            bucketed[pos] = (c << 7) | (r & 127);
        }
    }
}

// ---------------------------------------------------------------------------
// K4: fine counting sort inside each 128-row bucket. bucketStart recomputed
// locally (tree-reduce over binTotal[0..bin)). Emits meta (offs,cnt,dis packed
// int4 for agg), dis (for gemm epilogue) and the final csr segment.
__global__ __launch_bounds__(TPB) void finecsr_kernel(const int* __restrict__ bucketed,
                                                      const int* __restrict__ binTotal,
                                                      int4* __restrict__ meta,
                                                      float* __restrict__ dis,
                                                      int* __restrict__ csr, int N) {
    __shared__ int c128[128];
    __shared__ int cur128[128];
    __shared__ int sm[TPB];
    __shared__ int red[TPB];
    int bin = blockIdx.x;
    int tid = threadIdx.x;

    // s = sum(binTotal[0..bin)) ; m = binTotal[bin]
    int part = 0;
    for (int i = tid; i < bin; i += TPB) part += binTotal[i];
    red[tid] = part;
    __syncthreads();
    for (int o = TPB / 2; o > 0; o >>= 1) {
        if (tid < o) red[tid] += red[tid + o];
        __syncthreads();
    }
    int s = red[0];
    int m = binTotal[bin];

    if (tid < 128) c128[tid] = 0;
    __syncthreads();
    for (int i = tid; i < m; i += TPB) atomicAdd(&c128[bucketed[s + i] & 127], 1);
    __syncthreads();

    int v = (tid < 128) ? c128[tid] : 0;
    sm[tid] = v;
    __syncthreads();
    for (int o = 1; o < 128; o <<= 1) {
        int x = (tid >= o) ? sm[tid - o] : 0;
        __syncthreads();
        sm[tid] += x;
        __syncthreads();
    }
    if (tid < 128) {
        int excl = sm[tid] - v;
        int r = bin * 128 + tid;
        if (r < N) {
            float dv = rsqrtf((float)v + 1.0f);
            meta[r] = make_int4(s + excl, v, __float_as_int(dv), 0);
            dis[r] = dv;
        }
        cur128[tid] = s + excl;
    }
    __syncthreads();
    for (int i = tid; i < m; i += TPB) {
        int p = bucketed[s + i];
        int pos = atomicAdd(&cur128[p & 127], 1);
        csr[pos] = p >> 7;
    }
}

// ---------------------------------------------------------------------------
// MFMA bf16 GEMM: Hb[r, :] = bf16( dis[r] * (X[r,:] @ W^T + b) ),  K = 128.
// BM=128 rows/block, BN = 128 or 64 cols. X (fp32 or bf16) and W (fp32) are
// cast to bf16 and staged in LDS with row stride 136 shorts (272 B) so the
// per-fragment ds_read_b128 spreads evenly over all 32 banks.
// Block 0 additionally zeroes sentinel row N (agg's tail edges gather it).
// 4 waves: BN=128 -> each wave 64x64 (4x4 16x16 tiles); BN=64 -> 32x64 (2x4).
// Fragment layouts (verified, cdna_hip_programming §3):
//   A[m=lane&15][k=(lane>>4)*8+j], B[n=lane&15][k=(lane>>4)*8+j],
//   D: col=lane&15, row=(lane>>4)*4+reg.
template <int BN, bool INB16>
__global__ __launch_bounds__(256, 2) void gemm_mfma_kernel(const void* __restrict__ Xp,
                                                           const float* __restrict__ W,
                                                           const float* __restrict__ bias,
                                                           const float* __restrict__ dis,
                                                           unsigned short* __restrict__ Hb,
                                                           int N) {
    constexpr int XST = 136;  // padded LDS row stride (shorts); 272 B ≡ 4 banks shift/row
    __shared__ unsigned short Xs[128 * XST];
    __shared__ unsigned short Ws[BN * XST];

    const int tid = threadIdx.x;
    const int r0 = blockIdx.x * 128;

    // sentinel row N = 0 (BN/2 dwords)
    if (blockIdx.x == 0 && tid < (BN >> 1))
        ((unsigned*)Hb)[(size_t)N * (BN >> 1) + tid] = 0u;

    // ---- stage X tile (128 x 128) as bf16
    if (INB16) {
        const ushort4* Xv = (const ushort4*)Xp;
        for (int idx = tid; idx < 128 * 32; idx += 256) {
            int row = idx >> 5, q = idx & 31;
            int rg = r0 + row;
            if (rg >= N) rg = N - 1;
            *(ushort4*)&Xs[row * XST + q * 4] = Xv[(size_t)rg * 32 + q];
        }
    } else {
        const float4* Xv = (const float4*)Xp;
        for (int idx = tid; idx < 128 * 32; idx += 256) {
            int row = idx >> 5, q = idx & 31;
            int rg = r0 + row;
            if (rg >= N) rg = N - 1;
            float4 v = Xv[(size_t)rg * 32 + q];
            ushort4 s = make_ushort4(f2bf(v.x), f2bf(v.y), f2bf(v.z), f2bf(v.w));
            *(ushort4*)&Xs[row * XST + q * 4] = s;
        }
    }
    // ---- stage W tile (BN x 128) as bf16
    {
        const float4* Wv = (const float4*)W;
        for (int idx = tid; idx < BN * 32; idx += 256) {
            int n = idx >> 5, q = idx & 31;
            float4 v = Wv[n * 32 + q];
            ushort4 s = make_ushort4(f2bf(v.x), f2bf(v.y), f2bf(v.z), f2bf(v.w));
            *(ushort4*)&Ws[n * XST + q * 4] = s;
        }
    }
    __syncthreads();

    constexpr int RT = (BN == 128) ? 4 : 2;  // 16-row tiles per wave
    constexpr int CT = 4;                    // 16-col tiles per wave
    const int wave = tid >> 6, lane = tid & 63;
    const int l15 = lane & 15, q8 = lane >> 4;
    const int row0 = (BN == 128) ? (wave & 1) * 64 : wave * 32;
    const int col0 = (BN == 128) ? (wave >> 1) * 64 : 0;

    f32x4 zero = {0.f, 0.f, 0.f, 0.f};
    f32x4 acc[RT][CT];
#pragma unroll
    for (int rt = 0; rt < RT; ++rt)
#pragma unroll
        for (int ct = 0; ct < CT; ++ct) acc[rt][ct] = zero;

#pragma unroll
    for (int ks = 0; ks < 4; ++ks) {
        int ko = ks * 32 + q8 * 8;
        bf16x8 a[RT], b[CT];
#pragma unroll
        for (int rt = 0; rt < RT; ++rt)
            a[rt] = *(const bf16x8*)&Xs[(row0 + rt * 16 + l15) * XST + ko];
#pragma unroll
        for (int ct = 0; ct < CT; ++ct)
            b[ct] = *(const bf16x8*)&Ws[(col0 + ct * 16 + l15) * XST + ko];
#pragma unroll
        for (int rt = 0; rt < RT; ++rt)
#pragma unroll
            for (int ct = 0; ct < CT; ++ct)
                acc[rt][ct] = __builtin_amdgcn_mfma_f32_16x16x32_bf16(
                    a[rt], b[ct], acc[rt][ct], 0, 0, 0);
    }

    // ---- epilogue: (+bias[col]) * dis[row], pack bf16
    float bv[CT];
#pragma unroll
    for (int ct = 0; ct < CT; ++ct) bv[ct] = bias[col0 + ct * 16 + l15];
#pragma unroll
    for (int rt = 0; rt < RT; ++rt)
#pragma unroll
        for (int r = 0; r < 4; ++r) {
            int row = r0 + row0 + rt * 16 + q8 * 4 + r;
            if (row < N) {
                float dn = dis[row];
#pragma unroll
                for (int ct = 0; ct < CT; ++ct)
                    Hb[(size_t)row * BN + col0 + ct * 16 + l15] =
                        f2bf((acc[rt][ct][r] + bv[ct]) * dn);
            }
        }
}

// ---------------------------------------------------------------------------
// Pull aggregation over pre-scaled bf16 H' (H'[n] = dis[n]*(XW+b)[n]):
//   out[i] = dis[i] * (H'[i] + sum_e H'[col_e]),  optional relu.
// v6: one wave per node. lane = LPR*g + fl; LPR lanes x 16B (uint4) cover a
// full source row: F=128: LPR=16, G=4 (4 edges/load); F=64: LPR=8, G=8
// (8 edges/load). Quads of 16 edge-slots (KQ=16/G loads), 2 quads deep —
// min work for a d<=16 node is ONE quad. Tail edges gather sentinel row N
// (zeroed by gemm) -> no mask math (v_pk_add_f32, 3 VALU/dword). Self row:
// group 0 only. Non-temporal output stores + csr loads keep L2 for H' lines.
// OB16: pack output to bf16 (for R1 feeding the bf16 MFMA gemm2).
template <int F, bool RELU, bool OB16>
__global__ __launch_bounds__(TPB) void agg_kernel(const unsigned short* __restrict__ Hb,
                                                  const int* __restrict__ csr,
                                                  const int4* __restrict__ meta,
                                                  void* __restrict__ outp, int N) {
    constexpr int RS = F / 2;        // row stride in dwords (64 or 32)
    constexpr int LPR = RS / 4;      // lanes per row (16 or 8), uint4 each
    constexpr int G = 64 / LPR;      // edge subgroups (4 or 8)
    constexpr int KQ = 16 / G;       // loads per 16-slot quad (4 or 2)
    constexpr int NW = 4;            // dwords per lane

    int w = (blockIdx.x * TPB + threadIdx.x) >> 6;
    if (w >= N) return;  // wave-uniform: whole wave exits together
    const int lane = threadIdx.x & 63;
    const int g = lane / LPR;        // edge subgroup
    const int fl = lane % LPR;       // feature-granule index

    int4 m = meta[w];
    const int s = m.x, d = m.y;
    const float di = __int_as_float(m.z);

    const unsigned* Hu = (const unsigned*)Hb;

    f32x2 acc2[NW];
#pragma unroll
    for (int t = 0; t < NW; ++t) acc2[t] = (f32x2){0.f, 0.f};

    auto accum_row = [&](const unsigned (&u)[NW]) {
#pragma unroll
        for (int t = 0; t < NW; ++t) {
            f32x2 lh;
            lh.x = bf16lo(u[t]);
            lh.y = bf16hi(u[t]);
            acc2[t] = pk_add(acc2[t], lh);
        }
    };
    auto load_row = [&](unsigned (&u)[NW], int r) {
        u32x4 v = *(const u32x4*)(Hu + (size_t)r * RS + fl * NW);
        u[0] = v.x; u[1] = v.y; u[2] = v.z; u[3] = v.w;
    };

    // ---- self term: group 0 only (other groups contribute 0)
    if (g == 0) {
        unsigned su[NW];
        load_row(su, w);
        accum_row(su);
    }

    for (int base = 0; base < d; base += 64) {
        int rem = d - base;
        if (rem > 64) rem = 64;
        int cl = (lane < rem) ? __builtin_nontemporal_load(csr + s + base + lane) : 0;

        for (int e = 0; e < rem; e += 32) {  // 2 quads x 16 slots
            int cc0[KQ];
#pragma unroll
            for (int k = 0; k < KQ; ++k) {
                int idx = e + k * G + g;
                int raw = __shfl(cl, idx & 63);
                cc0[k] = (idx < rem) ? raw : N;   // tail -> zero sentinel row
            }
            unsigned u0[KQ][NW];
#pragma unroll
            for (int k = 0; k < KQ; ++k) load_row(u0[k], cc0[k]);

            const bool two = (e + 16) < rem;      // wave-uniform
            int cc1[KQ];
            unsigned u1[KQ][NW];
            if (two) {
#pragma unroll
                for (int k = 0; k < KQ; ++k) {
                    int idx = e + 16 + k * G + g;
                    int raw = __shfl(cl, idx & 63);
                    cc1[k] = (idx < rem) ? raw : N;
                }
#pragma unroll
                for (int k = 0; k < KQ; ++k) load_row(u1[k], cc1[k]);
            }
#pragma unroll
            for (int k = 0; k < KQ; ++k) accum_row(u0[k]);
            if (two) {
#pragma unroll
                for (int k = 0; k < KQ; ++k) accum_row(u1[k]);
            }
        }
    }

    // ---- fold the G edge-subgroups (lanes fl, fl+LPR, ... share features)
#pragma unroll
    for (int off = LPR; off < 64; off <<= 1)
#pragma unroll
        for (int t = 0; t < NW; ++t) {
            acc2[t].x += __shfl_xor(acc2[t].x, off);
            acc2[t].y += __shfl_xor(acc2[t].y, off);
        }

#pragma unroll
    for (int t = 0; t < NW; ++t) {
        acc2[t].x *= di;
        acc2[t].y *= di;
        if (RELU) {
            acc2[t].x = fmaxf(acc2[t].x, 0.0f);
            acc2[t].y = fmaxf(acc2[t].y, 0.0f);
        }
    }

    // ---- store: lanes 0..LPR-1 hold the full row, contiguous; non-temporal
    if (lane < LPR) {
        if constexpr (OB16) {
            u32x4 dw;
            dw.x = (unsigned)f2bf(acc2[0].x) | ((unsigned)f2bf(acc2[0].y) << 16);
            dw.y = (unsigned)f2bf(acc2[1].x) | ((unsigned)f2bf(acc2[1].y) << 16);
            dw.z = (unsigned)f2bf(acc2[2].x) | ((unsigned)f2bf(acc2[2].y) << 16);
            dw.w = (unsigned)f2bf(acc2[3].x) | ((unsigned)f2bf(acc2[3].y) << 16);
            unsigned* op = (unsigned*)outp;
            __builtin_nontemporal_store(dw, (u32x4*)(op + (size_t)w * RS + fl * NW));
        } else {
            f32x4 v0 = {acc2[0].x, acc2[0].y, acc2[1].x, acc2[1].y};
            f32x4 v1 = {acc2[2].x, acc2[2].y, acc2[3].x, acc2[3].y};
            f32x4* op = (f32x4*)outp;  // out row = F floats = F/4 f32x4s
            __builtin_nontemporal_store(v0, op + (size_t)w * (F / 4) + fl * 2);
            __builtin_nontemporal_store(v1, op + (size_t)w * (F / 4) + fl * 2 + 1);
        }
    }
}

// ---------------------------------------------------------------------------
extern "C" void kernel_launch(void* const* d_in, const int* in_sizes, int n_in,
                              void* d_out, int out_size, void* d_ws, size_t ws_size,
                              hipStream_t stream) {
    const float* x  = (const float*)d_in[0];
    const void*  ei = d_in[1];
    const float* W1 = (const float*)d_in[3];
    const float* b1 = (const float*)d_in[4];
    const float* W2 = (const float*)d_in[5];
    const float* b2 = (const float*)d_in[6];
    float* out = (float*)d_out;

    const int IN = 128, HID = 128;
    const int N = in_sizes[0] / IN;
    const int E = in_sizes[1] / 2;
    const int NB = (N + 127) >> 7;                 // coarse buckets (rows/128)
    const int CH = (E + NBLK_C - 1) / NBLK_C;      // edges per chunk block

    char* ws = (char*)d_ws;
    size_t off = 0;
    auto alloc = [&](size_t bytes) -> void* {
        void* p = (void*)(ws + off);
        off += (bytes + 255) & ~(size_t)255;
        return p;
    };
    int4*  meta     = (int4*)alloc((size_t)N * 16);
    float* dis      = (float*)alloc((size_t)N * 4);
    int*   row32    = (int*)alloc((size_t)E * 4);
    int*   col32    = (int*)alloc((size_t)E * 4);
    int*   bucketed = (int*)alloc((size_t)E * 4);
    int*   csr      = (int*)alloc((size_t)E * 4);
    int*   hist     = (int*)alloc((size_t)NB * NBLK_C * 4);
    int*   binTotal = (int*)alloc((size_t)NB * 4);
    unsigned short* H1b = (unsigned short*)alloc((size_t)(N + 1) * HID * 2);  // bf16 (+sentinel)
    unsigned short* R1b = (unsigned short*)alloc((size_t)(N + 1) * HID * 2);  // bf16
    unsigned short* H2b = H1b;  // reuse: H1b dead after agg1

    // ---- CSR build: counting sort, zero global atomics (4 launches, R2 form)
    hist_extract_kernel<<<NBLK_C, TPB_C, 0, stream>>>(ei, E, CH, row32, col32,
                                                      hist, NB, N);
    colscan_kernel<<<NB, NBLK_C, 0, stream>>>(hist, binTotal);
    scatter_kernel<<<NBLK_C, TPB_C, 0, stream>>>(row32, col32, E, CH, hist, binTotal,
                                                 bucketed, NB, N);
    finecsr_kernel<<<NB, TPB, 0, stream>>>(bucketed, binTotal, meta, dis, csr, N);

    int ngrid = (N + 127) / 128;
    int agrid = (N + 3) / 4;

    // layer 1: H1b = bf16(dis .* (X@W1^T + b1)) ; R1b = bf16(relu(dis .* (self+gather)))
    gemm_mfma_kernel<128, false><<<ngrid, 256, 0, stream>>>(x, W1, b1, dis, H1b, N);
    agg_kernel<128, true, true><<<agrid, TPB, 0, stream>>>(H1b, csr, meta, R1b, N);

    // layer 2: H2b = bf16(dis .* (R1b@W2^T + b2)) ; out = dis .* (self + gather)
    gemm_mfma_kernel<64, true><<<ngrid, 256, 0, stream>>>(R1b, W2, b2, dis, H2b, N);
    agg_kernel<64, false, false><<<agrid, TPB, 0, stream>>>(H2b, csr, meta, out, N);
}

// Round 9
// 278.170 us; speedup vs baseline: 1.0367x; 1.0367x over previous
//
#include <hip/hip_runtime.h>
#include <hip/hip_bf16.h>
#include <stdint.h>

// GCN 2-layer forward: out = A_hat @ relu(A_hat @ (X W1^T + b1)) W2^T + b2
// A_hat = D^-1/2 (A + I) D^-1/2, pull-based CSR aggregation.
// GEMMs use bf16 MFMA (16x16x32), fp32 accumulate; epilogue pre-scales rows by
// dis[n], stores H' in BF16, and zeroes sentinel row N (tail gathers hit it).
// Agg v7: one wave per node, non-persistent. Row split across LPR lanes x 16B
// (uint4); quads of 16 edge-slots (KQ=16/G loads per quad), 2 quads deep.
// Tail edges gather sentinel row N (zeroed by gemm) -> no mask math;
// v_pk_add_f32 packed accumulate.
// NT discipline (consumer-aware — R6-R8 lesson: nt on a buffer that a LATER
// kernel reads forces that consumer to re-fetch; agg1's nt R1b store cost
// gemm2 its L2 hits): agg1 = NO nt (R1b -> gemm2, csr -> agg2 both reused);
// agg2 = nt store (final out, never re-read) + nt csr load (last use).
// agg1 is at the L2-miss/L3 fabric ceiling for random 256B gathers:
// ~3.8 TB/s / FETCH ~187MB (~= 8 XCDs x footprint) across 6 structures.
// CSR build = 4-launch counting sort, zero global atomics: hist (stages
// row32/col32 int32) -> colscan -> scatter (fused in-LDS binTotal scan) ->
// finecsr (tree-reduce bucketStart).

#define TPB 256
#define NBLK_C 256            // edge chunks (blocks) in hist/scatter passes
#define TPB_C 1024            // threads per chunk block
#define MAX_NB 2048           // LDS arrays; scan paths assume NB <= 1024

typedef __attribute__((ext_vector_type(8))) __bf16 bf16x8;
typedef __attribute__((ext_vector_type(4))) float f32x4;
typedef __attribute__((ext_vector_type(2))) float f32x2;
typedef __attribute__((ext_vector_type(4))) unsigned int u32x4;

__device__ __forceinline__ float bf16lo(unsigned u) { return __uint_as_float(u << 16); }
__device__ __forceinline__ float bf16hi(unsigned u) { return __uint_as_float(u & 0xffff0000u); }
__device__ __forceinline__ unsigned short f2bf(float f) {
    unsigned u = __float_as_uint(f);
    return (unsigned short)((u + 0x7fff + ((u >> 16) & 1)) >> 16);  // RNE
}
// packed 2xfp32 add (VOP3P, full-rate): one instr for both bf16 halves
__device__ __forceinline__ f32x2 pk_add(f32x2 a, f32x2 b) {
    f32x2 d;
    asm("v_pk_add_f32 %0, %1, %2" : "=v"(d) : "v"(a), "v"(b));
    return d;
}

// ---------------------------------------------------------------------------
// K1: unpack edge_index -> row32/col32 staging AND per-block coarse-bucket
// histogram (bucket = row >> 7). Dtype probe (int64 vs int32) per-block by
// wave 0: int64 inputs (values < 2^31) have every odd 32-bit word of the
// first 64 row entries == 0. Validity predicate matches scatter exactly.
__global__ __launch_bounds__(TPB_C) void hist_extract_kernel(const void* __restrict__ ei, int E,
                                                             int CH,
                                                             int* __restrict__ row32,
                                                             int* __restrict__ col32,
                                                             int* __restrict__ hist,
                                                             int NB, int N) {
    __shared__ int h[MAX_NB];
    __shared__ int s_is64;
    int tid = threadIdx.x;
    if (tid < 64) {
        int x = ((const int*)ei)[2 * tid + 1];
        unsigned long long b = __ballot(x != 0);
        if (tid == 0) s_is64 = (b == 0ull);
    }
    for (int bin = tid; bin < NB; bin += TPB_C) h[bin] = 0;
    __syncthreads();

    int b = blockIdx.x;
    int s = b * CH;
    int end = min(E, s + CH);
    int is64 = s_is64;
    unsigned uN = (unsigned)N;
    if (is64) {
        const long long* p = (const long long*)ei;
        for (int e = s + tid; e < end; e += TPB_C) {
            int r = (int)p[e];
            int c = (int)p[E + e];
            row32[e] = r;
            col32[e] = c;
            if ((unsigned)r < uN && (unsigned)c < uN) atomicAdd(&h[r >> 7], 1);
        }
    } else {
        const int* p = (const int*)ei;
        for (int e = s + tid; e < end; e += TPB_C) {
            int r = p[e];
            int c = p[E + e];
            row32[e] = r;
            col32[e] = c;
            if ((unsigned)r < uN && (unsigned)c < uN) atomicAdd(&h[r >> 7], 1);
        }
    }
    __syncthreads();
    for (int bin = tid; bin < NB; bin += TPB_C) hist[bin * NBLK_C + b] = h[bin];
}

// ---------------------------------------------------------------------------
// K2: per-bucket exclusive scan across the NBLK_C block histograms (in place);
// emits binTotal[bin]. One block per bucket, TPB == NBLK_C.
__global__ __launch_bounds__(NBLK_C) void colscan_kernel(int* __restrict__ hist,
                                                         int* __restrict__ binTotal) {
    __shared__ int sm[NBLK_C];
    int bin = blockIdx.x;
    int tid = threadIdx.x;
    int v = hist[bin * NBLK_C + tid];
    sm[tid] = v;
    __syncthreads();
    for (int o = 1; o < NBLK_C; o <<= 1) {
        int x = (tid >= o) ? sm[tid - o] : 0;
        __syncthreads();
        sm[tid] += x;
        __syncthreads();
    }
    hist[bin * NBLK_C + tid] = sm[tid] - v;  // exclusive within bucket
    if (tid == NBLK_C - 1) binTotal[bin] = sm[NBLK_C - 1];
}

// ---------------------------------------------------------------------------
// K3: place edges into coarse buckets from staged int32. Per-block LDS
// cursors seeded from an in-kernel LDS scan of binTotal (bucketStart) +
// per-(bin,block) hist prefix; packed = (col<<7) | (row&127). NB <= 1024.
__global__ __launch_bounds__(TPB_C) void scatter_kernel(const int* __restrict__ row32,
                                                        const int* __restrict__ col32, int E,
                                                        int CH,
                                                        const int* __restrict__ hist,
                                                        const int* __restrict__ binTotal,
                                                        int* __restrict__ bucketed,
                                                        int NB, int N) {
    __shared__ int cur[MAX_NB];
    __shared__ int sm2[TPB_C];
    int tid = threadIdx.x;
    int b = blockIdx.x;

    // exclusive scan of binTotal (3KB, L2-hot) -> bucketStart, fused in-LDS
    int v = (tid < NB) ? binTotal[tid] : 0;
    sm2[tid] = v;
    __syncthreads();
    for (int o = 1; o < TPB_C; o <<= 1) {
        int x = (tid >= o) ? sm2[tid - o] : 0;
        __syncthreads();
        sm2[tid] += x;
        __syncthreads();
    }
    if (tid < NB) cur[tid] = (sm2[tid] - v) + hist[tid * NBLK_C + b];
    __syncthreads();

    int s = b * CH;
    int end = min(E, s + CH);
    unsigned uN = (unsigned)N;
    for (int e = s + tid; e < end; e += TPB_C) {
        int r = row32[e];
        int c = col32[e];
        if ((unsigned)r < uN && (unsigned)c < uN) {
            int pos = atomicAdd(&cur[r >> 7], 1);
            bucketed[pos] = (c << 7) | (r & 127);
        }
    }
}

// ---------------------------------------------------------------------------
// K4: fine counting sort inside each 128-row bucket. bucketStart recomputed
// locally (tree-reduce over binTotal[0..bin)). Emits meta (offs,cnt,dis packed
// int4 for agg), dis (for gemm epilogue) and the final csr segment.
__global__ __launch_bounds__(TPB) void finecsr_kernel(const int* __restrict__ bucketed,
                                                      const int* __restrict__ binTotal,
                                                      int4* __restrict__ meta,
                                                      float* __restrict__ dis,
                                                      int* __restrict__ csr, int N) {
    __shared__ int c128[128];
    __shared__ int cur128[128];
    __shared__ int sm[TPB];
    __shared__ int red[TPB];
    int bin = blockIdx.x;
    int tid = threadIdx.x;

    // s = sum(binTotal[0..bin)) ; m = binTotal[bin]
    int part = 0;
    for (int i = tid; i < bin; i += TPB) part += binTotal[i];
    red[tid] = part;
    __syncthreads();
    for (int o = TPB / 2; o > 0; o >>= 1) {
        if (tid < o) red[tid] += red[tid + o];
        __syncthreads();
    }
    int s = red[0];
    int m = binTotal[bin];

    if (tid < 128) c128[tid] = 0;
    __syncthreads();
    for (int i = tid; i < m; i += TPB) atomicAdd(&c128[bucketed[s + i] & 127], 1);
    __syncthreads();

    int v = (tid < 128) ? c128[tid] : 0;
    sm[tid] = v;
    __syncthreads();
    for (int o = 1; o < 128; o <<= 1) {
        int x = (tid >= o) ? sm[tid - o] : 0;
        __syncthreads();
        sm[tid] += x;
        __syncthreads();
    }
    if (tid < 128) {
        int excl = sm[tid] - v;
        int r = bin * 128 + tid;
        if (r < N) {
            float dv = rsqrtf((float)v + 1.0f);
            meta[r] = make_int4(s + excl, v, __float_as_int(dv), 0);
            dis[r] = dv;
        }
        cur128[tid] = s + excl;
    }
    __syncthreads();
    for (int i = tid; i < m; i += TPB) {
        int p = bucketed[s + i];
        int pos = atomicAdd(&cur128[p & 127], 1);
        csr[pos] = p >> 7;
    }
}

// ---------------------------------------------------------------------------
// MFMA bf16 GEMM: Hb[r, :] = bf16( dis[r] * (X[r,:] @ W^T + b) ),  K = 128.
// BM=128 rows/block, BN = 128 or 64 cols. X (fp32 or bf16) and W (fp32) are
// cast to bf16 and staged in LDS with row stride 136 shorts (272 B) so the
// per-fragment ds_read_b128 spreads evenly over all 32 banks.
// Block 0 additionally zeroes sentinel row N (agg's tail edges gather it).
// 4 waves: BN=128 -> each wave 64x64 (4x4 16x16 tiles); BN=64 -> 32x64 (2x4).
// Fragment layouts (verified, cdna_hip_programming §3):
//   A[m=lane&15][k=(lane>>4)*8+j], B[n=lane&15][k=(lane>>4)*8+j],
//   D: col=lane&15, row=(lane>>4)*4+reg.
template <int BN, bool INB16>
__global__ __launch_bounds__(256, 2) void gemm_mfma_kernel(const void* __restrict__ Xp,
                                                           const float* __restrict__ W,
                                                           const float* __restrict__ bias,
                                                           const float* __restrict__ dis,
                                                           unsigned short* __restrict__ Hb,
                                                           int N) {
    constexpr int XST = 136;  // padded LDS row stride (shorts); 272 B ≡ 4 banks shift/row
    __shared__ unsigned short Xs[128 * XST];
    __shared__ unsigned short Ws[BN * XST];

    const int tid = threadIdx.x;
    const int r0 = blockIdx.x * 128;

    // sentinel row N = 0 (BN/2 dwords)
    if (blockIdx.x == 0 && tid < (BN >> 1))
        ((unsigned*)Hb)[(size_t)N * (BN >> 1) + tid] = 0u;

    // ---- stage X tile (128 x 128) as bf16
    if (INB16) {
        const ushort4* Xv = (const ushort4*)Xp;
        for (int idx = tid; idx < 128 * 32; idx += 256) {
            int row = idx >> 5, q = idx & 31;
            int rg = r0 + row;
            if (rg >= N) rg = N - 1;
            *(ushort4*)&Xs[row * XST + q * 4] = Xv[(size_t)rg * 32 + q];
        }
    } else {
        const float4* Xv = (const float4*)Xp;
        for (int idx = tid; idx < 128 * 32; idx += 256) {
            int row = idx >> 5, q = idx & 31;
            int rg = r0 + row;
            if (rg >= N) rg = N - 1;
            float4 v = Xv[(size_t)rg * 32 + q];
            ushort4 s = make_ushort4(f2bf(v.x), f2bf(v.y), f2bf(v.z), f2bf(v.w));
            *(ushort4*)&Xs[row * XST + q * 4] = s;
        }
    }
    // ---- stage W tile (BN x 128) as bf16
    {
        const float4* Wv = (const float4*)W;
        for (int idx = tid; idx < BN * 32; idx += 256) {
            int n = idx >> 5, q = idx & 31;
            float4 v = Wv[n * 32 + q];
            ushort4 s = make_ushort4(f2bf(v.x), f2bf(v.y), f2bf(v.z), f2bf(v.w));
            *(ushort4*)&Ws[n * XST + q * 4] = s;
        }
    }
    __syncthreads();

    constexpr int RT = (BN == 128) ? 4 : 2;  // 16-row tiles per wave
    constexpr int CT = 4;                    // 16-col tiles per wave
    const int wave = tid >> 6, lane = tid & 63;
    const int l15 = lane & 15, q8 = lane >> 4;
    const int row0 = (BN == 128) ? (wave & 1) * 64 : wave * 32;
    const int col0 = (BN == 128) ? (wave >> 1) * 64 : 0;

    f32x4 zero = {0.f, 0.f, 0.f, 0.f};
    f32x4 acc[RT][CT];
#pragma unroll
    for (int rt = 0; rt < RT; ++rt)
#pragma unroll
        for (int ct = 0; ct < CT; ++ct) acc[rt][ct] = zero;

#pragma unroll
    for (int ks = 0; ks < 4; ++ks) {
        int ko = ks * 32 + q8 * 8;
        bf16x8 a[RT], b[CT];
#pragma unroll
        for (int rt = 0; rt < RT; ++rt)
            a[rt] = *(const bf16x8*)&Xs[(row0 + rt * 16 + l15) * XST + ko];
#pragma unroll
        for (int ct = 0; ct < CT; ++ct)
            b[ct] = *(const bf16x8*)&Ws[(col0 + ct * 16 + l15) * XST + ko];
#pragma unroll
        for (int rt = 0; rt < RT; ++rt)
#pragma unroll
            for (int ct = 0; ct < CT; ++ct)
                acc[rt][ct] = __builtin_amdgcn_mfma_f32_16x16x32_bf16(
                    a[rt], b[ct], acc[rt][ct], 0, 0, 0);
    }

    // ---- epilogue: (+bias[col]) * dis[row], pack bf16
    float bv[CT];
#pragma unroll
    for (int ct = 0; ct < CT; ++ct) bv[ct] = bias[col0 + ct * 16 + l15];
#pragma unroll
    for (int rt = 0; rt < RT; ++rt)
#pragma unroll
        for (int r = 0; r < 4; ++r) {
            int row = r0 + row0 + rt * 16 + q8 * 4 + r;
            if (row < N) {
                float dn = dis[row];
#pragma unroll
                for (int ct = 0; ct < CT; ++ct)
                    Hb[(size_t)row * BN + col0 + ct * 16 + l15] =
                        f2bf((acc[rt][ct][r] + bv[ct]) * dn);
            }
        }
}

// ---------------------------------------------------------------------------
// Pull aggregation over pre-scaled bf16 H' (H'[n] = dis[n]*(XW+b)[n]):
//   out[i] = dis[i] * (H'[i] + sum_e H'[col_e]),  optional relu.
// v7: one wave per node. lane = LPR*g + fl; LPR lanes x 16B (uint4) cover a
// full source row: F=128: LPR=16, G=4 (4 edges/load); F=64: LPR=8, G=8
// (8 edges/load). Quads of 16 edge-slots (KQ=16/G loads), 2 quads deep —
// min work for a d<=16 node is ONE quad. Tail edges gather sentinel row N
// (zeroed by gemm) -> no mask math (v_pk_add_f32, 3 VALU/dword). Self row:
// group 0 only. NT template params: NTLD (csr loads) / NTST (output stores)
// only when no later kernel re-reads that buffer (agg2 only).
// OB16: pack output to bf16 (for R1 feeding the bf16 MFMA gemm2).
template <int F, bool RELU, bool OB16, bool NTLD, bool NTST>
__global__ __launch_bounds__(TPB) void agg_kernel(const unsigned short* __restrict__ Hb,
                                                  const int* __restrict__ csr,
                                                  const int4* __restrict__ meta,
                                                  void* __restrict__ outp, int N) {
    constexpr int RS = F / 2;        // row stride in dwords (64 or 32)
    constexpr int LPR = RS / 4;      // lanes per row (16 or 8), uint4 each
    constexpr int G = 64 / LPR;      // edge subgroups (4 or 8)
    constexpr int KQ = 16 / G;       // loads per 16-slot quad (4 or 2)
    constexpr int NW = 4;            // dwords per lane

    int w = (blockIdx.x * TPB + threadIdx.x) >> 6;
    if (w >= N) return;  // wave-uniform: whole wave exits together
    const int lane = threadIdx.x & 63;
    const int g = lane / LPR;        // edge subgroup
    const int fl = lane % LPR;       // feature-granule index

    int4 m = meta[w];
    const int s = m.x, d = m.y;
    const float di = __int_as_float(m.z);

    const unsigned* Hu = (const unsigned*)Hb;

    f32x2 acc2[NW];
#pragma unroll
    for (int t = 0; t < NW; ++t) acc2[t] = (f32x2){0.f, 0.f};

    auto accum_row = [&](const unsigned (&u)[NW]) {
#pragma unroll
        for (int t = 0; t < NW; ++t) {
            f32x2 lh;
            lh.x = bf16lo(u[t]);
            lh.y = bf16hi(u[t]);
            acc2[t] = pk_add(acc2[t], lh);
        }
    };
    auto load_row = [&](unsigned (&u)[NW], int r) {
        u32x4 v = *(const u32x4*)(Hu + (size_t)r * RS + fl * NW);
        u[0] = v.x; u[1] = v.y; u[2] = v.z; u[3] = v.w;
    };

    // ---- self term: group 0 only (other groups contribute 0)
    if (g == 0) {
        unsigned su[NW];
        load_row(su, w);
        accum_row(su);
    }

    for (int base = 0; base < d; base += 64) {
        int rem = d - base;
        if (rem > 64) rem = 64;
        int cl;
        if (lane < rem) {
            if constexpr (NTLD) cl = __builtin_nontemporal_load(csr + s + base + lane);
            else                cl = csr[s + base + lane];
        } else cl = 0;

        for (int e = 0; e < rem; e += 32) {  // 2 quads x 16 slots
            int cc0[KQ];
#pragma unroll
            for (int k = 0; k < KQ; ++k) {
                int idx = e + k * G + g;
                int raw = __shfl(cl, idx & 63);
                cc0[k] = (idx < rem) ? raw : N;   // tail -> zero sentinel row
            }
            unsigned u0[KQ][NW];
#pragma unroll
            for (int k = 0; k < KQ; ++k) load_row(u0[k], cc0[k]);

            const bool two = (e + 16) < rem;      // wave-uniform
            int cc1[KQ];
            unsigned u1[KQ][NW];
            if (two) {
#pragma unroll
                for (int k = 0; k < KQ; ++k) {
                    int idx = e + 16 + k * G + g;
                    int raw = __shfl(cl, idx & 63);
                    cc1[k] = (idx < rem) ? raw : N;
                }
#pragma unroll
                for (int k = 0; k < KQ; ++k) load_row(u1[k], cc1[k]);
            }
#pragma unroll
            for (int k = 0; k < KQ; ++k) accum_row(u0[k]);
            if (two) {
#pragma unroll
                for (int k = 0; k < KQ; ++k) accum_row(u1[k]);
            }
        }
    }

    // ---- fold the G edge-subgroups (lanes fl, fl+LPR, ... share features)
#pragma unroll
    for (int off = LPR; off < 64; off <<= 1)
#pragma unroll
        for (int t = 0; t < NW; ++t) {
            acc2[t].x += __shfl_xor(acc2[t].x, off);
            acc2[t].y += __shfl_xor(acc2[t].y, off);
        }

#pragma unroll
    for (int t = 0; t < NW; ++t) {
        acc2[t].x *= di;
        acc2[t].y *= di;
        if (RELU) {
            acc2[t].x = fmaxf(acc2[t].x, 0.0f);
            acc2[t].y = fmaxf(acc2[t].y, 0.0f);
        }
    }

    // ---- store: lanes 0..LPR-1 hold the full row, contiguous
    if (lane < LPR) {
        if constexpr (OB16) {
            u32x4 dw;
            dw.x = (unsigned)f2bf(acc2[0].x) | ((unsigned)f2bf(acc2[0].y) << 16);
            dw.y = (unsigned)f2bf(acc2[1].x) | ((unsigned)f2bf(acc2[1].y) << 16);
            dw.z = (unsigned)f2bf(acc2[2].x) | ((unsigned)f2bf(acc2[2].y) << 16);
            dw.w = (unsigned)f2bf(acc2[3].x) | ((unsigned)f2bf(acc2[3].y) << 16);
            unsigned* op = (unsigned*)outp;
            u32x4* dst = (u32x4*)(op + (size_t)w * RS + fl * NW);
            if constexpr (NTST) __builtin_nontemporal_store(dw, dst);
            else                *dst = dw;
        } else {
            f32x4 v0 = {acc2[0].x, acc2[0].y, acc2[1].x, acc2[1].y};
            f32x4 v1 = {acc2[2].x, acc2[2].y, acc2[3].x, acc2[3].y};
            f32x4* op = (f32x4*)outp;  // out row = F floats = F/4 f32x4s
            f32x4* d0 = op + (size_t)w * (F / 4) + fl * 2;
            if constexpr (NTST) {
                __builtin_nontemporal_store(v0, d0);
                __builtin_nontemporal_store(v1, d0 + 1);
            } else {
                d0[0] = v0;
                d0[1] = v1;
            }
        }
    }
}

// ---------------------------------------------------------------------------
extern "C" void kernel_launch(void* const* d_in, const int* in_sizes, int n_in,
                              void* d_out, int out_size, void* d_ws, size_t ws_size,
                              hipStream_t stream) {
    const float* x  = (const float*)d_in[0];
    const void*  ei = d_in[1];
    const float* W1 = (const float*)d_in[3];
    const float* b1 = (const float*)d_in[4];
    const float* W2 = (const float*)d_in[5];
    const float* b2 = (const float*)d_in[6];
    float* out = (float*)d_out;

    const int IN = 128, HID = 128;
    const int N = in_sizes[0] / IN;
    const int E = in_sizes[1] / 2;
    const int NB = (N + 127) >> 7;                 // coarse buckets (rows/128)
    const int CH = (E + NBLK_C - 1) / NBLK_C;      // edges per chunk block

    char* ws = (char*)d_ws;
    size_t off = 0;
    auto alloc = [&](size_t bytes) -> void* {
        void* p = (void*)(ws + off);
        off += (bytes + 255) & ~(size_t)255;
        return p;
    };
    int4*  meta     = (int4*)alloc((size_t)N * 16);
    float* dis      = (float*)alloc((size_t)N * 4);
    int*   row32    = (int*)alloc((size_t)E * 4);
    int*   col32    = (int*)alloc((size_t)E * 4);
    int*   bucketed = (int*)alloc((size_t)E * 4);
    int*   csr      = (int*)alloc((size_t)E * 4);
    int*   hist     = (int*)alloc((size_t)NB * NBLK_C * 4);
    int*   binTotal = (int*)alloc((size_t)NB * 4);
    unsigned short* H1b = (unsigned short*)alloc((size_t)(N + 1) * HID * 2);  // bf16 (+sentinel)
    unsigned short* R1b = (unsigned short*)alloc((size_t)(N + 1) * HID * 2);  // bf16
    unsigned short* H2b = H1b;  // reuse: H1b dead after agg1

    // ---- CSR build: counting sort, zero global atomics (4 launches)
    hist_extract_kernel<<<NBLK_C, TPB_C, 0, stream>>>(ei, E, CH, row32, col32,
                                                      hist, NB, N);
    colscan_kernel<<<NB, NBLK_C, 0, stream>>>(hist, binTotal);
    scatter_kernel<<<NBLK_C, TPB_C, 0, stream>>>(row32, col32, E, CH, hist, binTotal,
                                                 bucketed, NB, N);
    finecsr_kernel<<<NB, TPB, 0, stream>>>(bucketed, binTotal, meta, dis, csr, N);

    int ngrid = (N + 127) / 128;
    int agrid = (N + 3) / 4;

    // layer 1: H1b = bf16(dis .* (X@W1^T + b1)) ; R1b = bf16(relu(dis .* (self+gather)))
    // agg1: NO nt — R1b feeds gemm2 and csr is re-read by agg2; keep both in L2.
    gemm_mfma_kernel<128, false><<<ngrid, 256, 0, stream>>>(x, W1, b1, dis, H1b, N);
    agg_kernel<128, true, true, false, false><<<agrid, TPB, 0, stream>>>(H1b, csr, meta,
                                                                         R1b, N);

    // layer 2: H2b = bf16(dis .* (R1b@W2^T + b2)) ; out = dis .* (self + gather)
    // agg2: nt on csr (last use) and out (never re-read).
    gemm_mfma_kernel<64, true><<<ngrid, 256, 0, stream>>>(R1b, W2, b2, dis, H2b, N);
    agg_kernel<64, false, false, true, true><<<agrid, TPB, 0, stream>>>(H2b, csr, meta,
                                                                        out, N);
}